// Round 5
// baseline (208.315 us; speedup 1.0000x reference)
//
#include <hip/hip_runtime.h>
#include <hip/hip_bf16.h>
#include <stdint.h>

// EdgeConv B=256,N=128,C=64,K=16 — round 5: fused kernel, round-4 MLP +
// PROVEN round-2 rank-count KNN (u64 (dist,idx) keys, contract-off math).
// - KNN: per wave, per row: 128 exact-tie u64 keys staged in per-wave LDS
//   (overlays X), rank = #smaller keys; ranks 1..16 scatter to knnL.
//   Distance formula pinned with `#pragma clang fp contract(off)`.
// - MLP: L0/L1 transposed orientation (weights=A, acts=B) -> inter-layer
//   transpose is 4x ds_write_b64; L2 normal so mean-pool is 8 shuffles.
//   BN scales folded into bf16 weights; offsets via acc init. L0 center
//   half hoisted to one per-wave M=16 GEMM (cLS, fp32).
// - LDS 51.2KB -> 3 blocks/CU. Grid 1024 blocks, 8 rows/wave.

#define EPSV 1e-3f
#define ST 72  // padded stride (bf16 elems) for hot X/w0dT/w1T rows: 144B

typedef __bf16 bf16x8 __attribute__((ext_vector_type(8)));
typedef float f32x4 __attribute__((ext_vector_type(4)));
union B8 { uint4 u; bf16x8 v; };

__device__ __forceinline__ unsigned f2ord(float f) {
  unsigned u = __float_as_uint(f);
  return (u & 0x80000000u) ? ~u : (u | 0x80000000u);
}
__device__ __forceinline__ unsigned short bf1(float x) {
  union { __hip_bfloat16 h; unsigned short u; } cv;
  cv.h = __float2bfloat16(x);
  return cv.u;
}
__device__ __forceinline__ unsigned pk2(float lo, float hi) {
  union { __hip_bfloat162 h; unsigned u; } cv;
  cv.h = __float22bfloat162_rn(float2{lo, hi});
  return cv.u;
}
// contraction-pinned distance math (matches rounds 1/2 which passed vs np)
__device__ __forceinline__ float r2of(float x, float y) {
#pragma clang fp contract(off)
  return __fadd_rn(__fmul_rn(x, x), __fmul_rn(y, y));
}
__device__ __forceinline__ float sqdist(float rn, float xn, float yn,
                                        float xc, float yc, float rc) {
#pragma clang fp contract(off)
  const float dot = __fadd_rn(__fmul_rn(xn, xc), __fmul_rn(yn, yc));
  return __fadd_rn(__fsub_rn(rn, __fmul_rn(2.0f, dot)), rc);
}

__global__ __launch_bounds__(256, 3) void fused_kernel(
    const float* __restrict__ pts, const float* __restrict__ feat,
    const float* __restrict__ w0, const float* __restrict__ g0,
    const float* __restrict__ b0, const float* __restrict__ m0,
    const float* __restrict__ v0, const float* __restrict__ w1,
    const float* __restrict__ g1, const float* __restrict__ b1,
    const float* __restrict__ m1, const float* __restrict__ v1,
    const float* __restrict__ w2, const float* __restrict__ g2,
    const float* __restrict__ b2, const float* __restrict__ m2,
    const float* __restrict__ v2, const float* __restrict__ wsc,
    const float* __restrict__ gsc, const float* __restrict__ bsc,
    const float* __restrict__ msc, const float* __restrict__ vsc,
    float* __restrict__ out) {
  __shared__ __align__(16) unsigned short w0dT[64 * ST];  // persistent, hot
  __shared__ __align__(16) unsigned short w1T[64 * ST];   // persistent, hot
  __shared__ __align__(16) char U[32768];                 // union region

  // phase-A layout of U (dead after sync #2):
  unsigned short* w0cT = (unsigned short*)U;              // [64][64]
  unsigned short* w2T = (unsigned short*)(U + 8192);      // [64][64]
  unsigned short* wscT = (unsigned short*)(U + 16384);    // [64][64]

  const int tid = threadIdx.x;
  const int wv = tid >> 6;
  const int lane = tid & 63;
  const int m = lane & 15;
  const int q4 = lane >> 4;

  unsigned short* CFB = (unsigned short*)(U + 24576) + wv * (16 * 64);

  // ---------------- stage weights, BN scale folded, bf16 ----------------
#pragma unroll
  for (int q = 0; q < 8; ++q) {
    const int v = tid + 256 * q;  // float4 idx into w0 (2048 total)
    const int i = v >> 4;         // 0..127 input channel
    const int c = (v & 15) << 2;  // output channel base
    const float4 w = ((const float4*)w0)[v];
    float s[4];
#pragma unroll
    for (int cc = 0; cc < 4; ++cc) s[cc] = g0[c + cc] / sqrtf(v0[c + cc] + EPSV);
    if (i < 64) {
      w0cT[(c + 0) * 64 + i] = bf1(w.x * s[0]);
      w0cT[(c + 1) * 64 + i] = bf1(w.y * s[1]);
      w0cT[(c + 2) * 64 + i] = bf1(w.z * s[2]);
      w0cT[(c + 3) * 64 + i] = bf1(w.w * s[3]);
    } else {
      const int i2 = i - 64;
      w0dT[(c + 0) * ST + i2] = bf1(w.x * s[0]);
      w0dT[(c + 1) * ST + i2] = bf1(w.y * s[1]);
      w0dT[(c + 2) * ST + i2] = bf1(w.z * s[2]);
      w0dT[(c + 3) * ST + i2] = bf1(w.w * s[3]);
    }
  }
#pragma unroll
  for (int q = 0; q < 4; ++q) {
    const int v = tid + 256 * q;  // 1024 float4 per matrix
    const int i = v >> 4;
    const int c = (v & 15) << 2;
    {
      const float4 w = ((const float4*)w1)[v];
#pragma unroll
      for (int cc = 0; cc < 4; ++cc) {
        const float s = g1[c + cc] / sqrtf(v1[c + cc] + EPSV);
        const float val = (cc == 0 ? w.x : cc == 1 ? w.y : cc == 2 ? w.z : w.w);
        w1T[(c + cc) * ST + i] = bf1(val * s);
      }
    }
    {
      const float4 w = ((const float4*)w2)[v];
#pragma unroll
      for (int cc = 0; cc < 4; ++cc) {
        const float s = g2[c + cc] / sqrtf(v2[c + cc] + EPSV);
        const float val = (cc == 0 ? w.x : cc == 1 ? w.y : cc == 2 ? w.z : w.w);
        w2T[(c + cc) * 64 + i] = bf1(val * s);
      }
    }
    {
      const float4 w = ((const float4*)wsc)[v];
#pragma unroll
      for (int cc = 0; cc < 4; ++cc) {
        const float s = gsc[c + cc] / sqrtf(vsc[c + cc] + EPSV);
        const float val = (cc == 0 ? w.x : cc == 1 ? w.y : cc == 2 ? w.z : w.w);
        wscT[(c + cc) * 64 + i] = bf1(val * s);
      }
    }
  }

  // ---- per-lane BN offsets ----
  f32x4 o1vv[4];  // L1 acc-init: c' = nt*16 + q4*4 + reg
#pragma unroll
  for (int nt = 0; nt < 4; ++nt)
#pragma unroll
    for (int r = 0; r < 4; ++r) {
      const int c = nt * 16 + q4 * 4 + r;
      const float s = g1[c] / sqrtf(v1[c] + EPSV);
      o1vv[nt][r] = b1[c] - m1[c] * s;
    }
  float o0s[4], o2s[4], oscs[4];  // c' = nt*16 + m
#pragma unroll
  for (int nt = 0; nt < 4; ++nt) {
    const int c = nt * 16 + m;
    o0s[nt] = b0[c] - m0[c] * (g0[c] / sqrtf(v0[c] + EPSV));
    o2s[nt] = b2[c] - m2[c] * (g2[c] / sqrtf(v2[c] + EPSV));
    oscs[nt] = bsc[c] - msc[c] * (gsc[c] / sqrtf(vsc[c] + EPSV));
  }
  __syncthreads();  // #1: weights staged

  const int row0 = blockIdx.x * 32 + wv * 8;  // this wave's 8 rows
  const int bb = row0 >> 7;
  const float* featb = feat + bb * (128 * 64);

  // ---- stage CFB: 8 center rows, bf16, [r][i] stride 64; zero rows 8..15 ----
  {
    const int r = lane >> 3, p = lane & 7;  // 8 rows x 8 lanes
    const float4* fr = (const float4*)(feat + (row0 + r) * 64);
    const float4 a = fr[p * 2 + 0], bq = fr[p * 2 + 1];
    uint4 u{pk2(a.x, a.y), pk2(a.z, a.w), pk2(bq.x, bq.y), pk2(bq.z, bq.w)};
    *(uint4*)&CFB[r * 64 + p * 8] = u;
    *(uint4*)&CFB[512 + lane * 8] = make_uint4(0u, 0u, 0u, 0u);  // rows 8..15
  }

  // ---- w2 B-frags to registers (before U is recycled) ----
  B8 w2f[4][2];
#pragma unroll
  for (int nt = 0; nt < 4; ++nt)
#pragma unroll
    for (int t = 0; t < 2; ++t)
      w2f[nt][t].u = *(const uint4*)&w2T[(nt * 16 + m) * 64 + t * 32 + q4 * 8];

  const f32x4 fzero = {0.f, 0.f, 0.f, 0.f};
  // ---- center-L0 GEMM and shortcut GEMM (normal orient, M=16, 8 valid) ----
  f32x4 cacc[4] = {fzero, fzero, fzero, fzero};
  f32x4 scf[4] = {fzero, fzero, fzero, fzero};
#pragma unroll
  for (int t = 0; t < 2; ++t) {
    B8 af;
    af.u = *(const uint4*)&CFB[m * 64 + t * 32 + q4 * 8];
#pragma unroll
    for (int nt = 0; nt < 4; ++nt) {
      B8 bf_;
      bf_.u = *(const uint4*)&w0cT[(nt * 16 + m) * 64 + t * 32 + q4 * 8];
      cacc[nt] = __builtin_amdgcn_mfma_f32_16x16x32_bf16(af.v, bf_.v, cacc[nt], 0, 0, 0);
      bf_.u = *(const uint4*)&wscT[(nt * 16 + m) * 64 + t * 32 + q4 * 8];
      scf[nt] = __builtin_amdgcn_mfma_f32_16x16x32_bf16(af.v, bf_.v, scf[nt], 0, 0, 0);
    }
  }
#pragma unroll
  for (int nt = 0; nt < 4; ++nt)
#pragma unroll
    for (int r = 0; r < 4; ++r) scf[nt][r] += oscs[nt];

  __syncthreads();  // #2: U weight area dead, per-wave areas live

  // phase-B layout of U: per-wave scratch
  char* pwb = U + wv * 8192;
  unsigned short* X = (unsigned short*)pwb;                       // [16][ST]
  float* cLS = (float*)(pwb + 2304);                              // [16][64]
  unsigned char* knnL = (unsigned char*)(pwb + 2304 + 4096);      // [8][16]

  // write cLS = center-L0 + o0 (only rows 0..7 used)
#pragma unroll
  for (int nt = 0; nt < 4; ++nt)
#pragma unroll
    for (int r = 0; r < 4; ++r)
      cLS[(q4 * 4 + r) * 64 + nt * 16 + m] = cacc[nt][r] + o0s[nt];

  // ------- KNN: round-2 rank-count, u64 (dist,idx) keys in LDS -------
  {
    unsigned long long* keysW = (unsigned long long*)pwb;  // overlays X, 1KB
    const float* pb = pts + bb * 256;
    const float xa = pb[2 * lane], ya = pb[2 * lane + 1];
    const float xb2 = pb[2 * lane + 128], yb2 = pb[2 * lane + 129];
    const float ra = r2of(xa, ya);
    const float rb = r2of(xb2, yb2);
    const int nbase = row0 & 127;
    for (int rr = 0; rr < 8; ++rr) {
      const int n = nbase + rr;
      const float xn = pb[2 * n], yn = pb[2 * n + 1];
      const float rn = r2of(xn, yn);
      const float d0 = sqdist(rn, xn, yn, xa, ya, ra);
      const float d1 = sqdist(rn, xn, yn, xb2, yb2, rb);
      const unsigned long long key0 =
          ((unsigned long long)f2ord(d0) << 32) | (unsigned)lane;
      const unsigned long long key1 =
          ((unsigned long long)f2ord(d1) << 32) | (unsigned)(lane + 64);
      keysW[lane] = key0;
      keysW[lane + 64] = key1;
      // same-wave in-order DS: all 128 writes precede the reads below
      int c0 = 0, c1 = 0;
#pragma unroll 8
      for (int j = 0; j < 128; j += 2) {
        const ulonglong2 kp = *(const ulonglong2*)&keysW[j];
        c0 += (kp.x < key0); c0 += (kp.y < key0);
        c1 += (kp.x < key1); c1 += (kp.y < key1);
      }
      // rank 0 = self (dropped); ranks 1..16 are the K neighbors
      if (c0 >= 1 && c0 <= 16) knnL[rr * 16 + c0 - 1] = (unsigned char)lane;
      if (c1 >= 1 && c1 <= 16) knnL[rr * 16 + c1 - 1] = (unsigned char)(lane + 64);
    }
  }

  // hoist all neighbor indices (one lgkm wait, kills per-row latency chain)
  const int kk = lane >> 2, pp = lane & 3;
  int jv[8];
#pragma unroll
  for (int rr = 0; rr < 8; ++rr) jv[rr] = knnL[rr * 16 + kk];

  // ---------------- row loop: 8 rows ----------------
  for (int qo = 0; qo < 2; ++qo) {
#pragma unroll
    for (int ri = 0; ri < 4; ++ri) {
      const int rr = qo * 4 + ri;
      const int row = row0 + rr;

      // stage diffs [k][i] bf16 (k = kk, 16 channels per lane)
      {
        const float4* np_ = (const float4*)(featb + jv[rr] * 64);
        const float4* cp_ = (const float4*)(feat + row * 64);
        const float4 n0 = np_[pp * 4 + 0], n1 = np_[pp * 4 + 1];
        const float4 n2 = np_[pp * 4 + 2], n3 = np_[pp * 4 + 3];
        const float4 c0 = cp_[pp * 4 + 0], c1 = cp_[pp * 4 + 1];
        const float4 c2 = cp_[pp * 4 + 2], c3 = cp_[pp * 4 + 3];
        uint4 u;
        u.x = pk2(n0.x - c0.x, n0.y - c0.y); u.y = pk2(n0.z - c0.z, n0.w - c0.w);
        u.z = pk2(n1.x - c1.x, n1.y - c1.y); u.w = pk2(n1.z - c1.z, n1.w - c1.w);
        *(uint4*)&X[kk * ST + pp * 16] = u;
        u.x = pk2(n2.x - c2.x, n2.y - c2.y); u.y = pk2(n2.z - c2.z, n2.w - c2.w);
        u.z = pk2(n3.x - c3.x, n3.y - c3.y); u.w = pk2(n3.z - c3.z, n3.w - c3.w);
        *(uint4*)&X[kk * ST + pp * 16 + 8] = u;
      }

      // ---- L0 (T-orient): D[c'][k], acc init = cLS row ----
      f32x4 acc[4];
#pragma unroll
      for (int nt = 0; nt < 4; ++nt)
        acc[nt] = *(const f32x4*)&cLS[rr * 64 + nt * 16 + q4 * 4];
#pragma unroll
      for (int t = 0; t < 2; ++t) {
        B8 bf_;
        bf_.u = *(const uint4*)&X[m * ST + t * 32 + q4 * 8];
#pragma unroll
        for (int nt = 0; nt < 4; ++nt) {
          B8 af;
          af.u = *(const uint4*)&w0dT[(nt * 16 + m) * ST + t * 32 + q4 * 8];
          acc[nt] = __builtin_amdgcn_mfma_f32_16x16x32_bf16(af.v, bf_.v, acc[nt], 0, 0, 0);
        }
      }
#pragma unroll
      for (int nt = 0; nt < 4; ++nt) {  // relu + write Y0^T -> X[k][c']
        uint2 wq;
        wq.x = pk2(fmaxf(acc[nt][0], 0.f), fmaxf(acc[nt][1], 0.f));
        wq.y = pk2(fmaxf(acc[nt][2], 0.f), fmaxf(acc[nt][3], 0.f));
        *(uint2*)&X[m * ST + nt * 16 + q4 * 4] = wq;
      }

      // ---- L1 (T-orient): acc init = o1 ----
#pragma unroll
      for (int nt = 0; nt < 4; ++nt) acc[nt] = o1vv[nt];
#pragma unroll
      for (int t = 0; t < 2; ++t) {
        B8 bf_;
        bf_.u = *(const uint4*)&X[m * ST + t * 32 + q4 * 8];
#pragma unroll
        for (int nt = 0; nt < 4; ++nt) {
          B8 af;
          af.u = *(const uint4*)&w1T[(nt * 16 + m) * ST + t * 32 + q4 * 8];
          acc[nt] = __builtin_amdgcn_mfma_f32_16x16x32_bf16(af.v, bf_.v, acc[nt], 0, 0, 0);
        }
      }
#pragma unroll
      for (int nt = 0; nt < 4; ++nt) {
        uint2 wq;
        wq.x = pk2(fmaxf(acc[nt][0], 0.f), fmaxf(acc[nt][1], 0.f));
        wq.y = pk2(fmaxf(acc[nt][2], 0.f), fmaxf(acc[nt][3], 0.f));
        *(uint2*)&X[m * ST + nt * 16 + q4 * 4] = wq;
      }

      // ---- L2 (normal orient): D[k][c'], B = w2 regs ----
#pragma unroll
      for (int nt = 0; nt < 4; ++nt) acc[nt] = fzero;
#pragma unroll
      for (int t = 0; t < 2; ++t) {
        B8 af;
        af.u = *(const uint4*)&X[m * ST + t * 32 + q4 * 8];
#pragma unroll
        for (int nt = 0; nt < 4; ++nt)
          acc[nt] = __builtin_amdgcn_mfma_f32_16x16x32_bf16(af.v, w2f[nt][t].v, acc[nt], 0, 0, 0);
      }

      // ---- BN offset + relu + mean over k + shortcut + store ----
      float pool[4];
#pragma unroll
      for (int nt = 0; nt < 4; ++nt) {
        float p = fmaxf(acc[nt][0] + o2s[nt], 0.f) + fmaxf(acc[nt][1] + o2s[nt], 0.f) +
                  fmaxf(acc[nt][2] + o2s[nt], 0.f) + fmaxf(acc[nt][3] + o2s[nt], 0.f);
        p += __shfl_xor(p, 16);
        p += __shfl_xor(p, 32);
        pool[nt] = p * 0.0625f;
      }
      if (q4 == qo) {
#pragma unroll
        for (int nt = 0; nt < 4; ++nt)
          out[row * 64 + nt * 16 + m] = fmaxf(scf[nt][ri] + pool[nt], 0.f);
      }
    }
  }
}

extern "C" void kernel_launch(void* const* d_in, const int* in_sizes, int n_in,
                              void* d_out, int out_size, void* d_ws, size_t ws_size,
                              hipStream_t stream) {
  const float* pts = (const float*)d_in[0];
  const float* feat = (const float*)d_in[1];
  const float* w0 = (const float*)d_in[2];
  const float* g0 = (const float*)d_in[3];
  const float* b0 = (const float*)d_in[4];
  const float* m0 = (const float*)d_in[5];
  const float* v0 = (const float*)d_in[6];
  const float* w1 = (const float*)d_in[7];
  const float* g1 = (const float*)d_in[8];
  const float* b1 = (const float*)d_in[9];
  const float* m1 = (const float*)d_in[10];
  const float* v1 = (const float*)d_in[11];
  const float* w2 = (const float*)d_in[12];
  const float* g2 = (const float*)d_in[13];
  const float* b2 = (const float*)d_in[14];
  const float* m2 = (const float*)d_in[15];
  const float* v2 = (const float*)d_in[16];
  const float* wsc = (const float*)d_in[17];
  const float* gsc = (const float*)d_in[18];
  const float* bsc = (const float*)d_in[19];
  const float* msc = (const float*)d_in[20];
  const float* vsc = (const float*)d_in[21];
  float* out = (float*)d_out;

  fused_kernel<<<dim3(1024), dim3(256), 0, stream>>>(
      pts, feat, w0, g0, b0, m0, v0, w1, g1, b1, m1, v1, w2, g2, b2, m2, v2,
      wsc, gsc, bsc, msc, vsc, out);
}